// Round 7
// baseline (991.107 us; speedup 1.0000x reference)
//
#include <hip/hip_runtime.h>

// ForexLSTM: 2-layer LSTM (B=1024, T=512, D=14, H=128) + batchnorm-over-batch + MLP(128->32->1)
//
// Round 17: cellP redistribution WITHOUT the constructs that triggered the spill storm.
// Evidence: R12 (no redistribution) = VGPR 256, WRITE 0.5MB. R14/R16 (redistribution via
// cred LDS + asm-"memory" waitcnt + sched_barrier(0) in-loop) = VGPR 128 + ~88MB scratch,
// regardless of launch-bounds/waves_per_eu attributes. Same pressure, different allocation
// -> the in-loop barriers/clobbers wrecked the scheduler's pressure estimate, not the
// occupancy target. Fix: redistribute through ds_bpermute (register crossbar):
//   - dest lane (nn=lane>>4, jj=lane&15) needs element jj&3 of C[g] from source lane
//     (jj>>2)*16+nn: 4 bpermutes/gate + 3 cndmask selects (static reg indices).
//     32 bpermutes/wave/phase, wave-synchronous, no LDS state, no barriers, no asm.
//   - cred arrays gone (LDS 122 -> 82 KB), no setprio, no sched_barrier: structure is
//     otherwise R12-exact (the build that allocated 256 VGPRs, __launch_bounds__(NT,1)).
//   - Keeps one-cellP-per-lane (R14-proven: VALUBusy 38 -> 23) + fused-reciprocal
//     activations (5 exp2 + 2 rcp) + wave-role merge + incremental x prefetch.

#define B_ 1024
#define T_ 512
#define D_ 14
#define H_ 128
#define NB 4
#define NT 512

#define L2E 1.44269504088896f
#define L2E2 2.88539008177793f

typedef _Float16 f16;
typedef _Float16 half4 __attribute__((ext_vector_type(4)));
typedef _Float16 half8 __attribute__((ext_vector_type(8)));
typedef float floatx4 __attribute__((ext_vector_type(4)));

__device__ __forceinline__ half8 ldfrag_s(const float* __restrict__ p, float s) {
    half8 r;
#pragma unroll
    for (int j = 0; j < 8; ++j) r[j] = (f16)(p[j] * s);
    return r;
}

#define MFMA(a, b, c) __builtin_amdgcn_mfma_f32_16x16x32_f16((a), (b), (c), 0, 0, 0)

// Fused LSTM cell epilogue on pre-scaled gates:
//   pi,pf,po = y*log2e ; pg = 2x*log2e ; cs = 2*log2e*c (scaled cell state, updated).
// Returns h in true units. 5 exp2 + 2 rcp.
__device__ __forceinline__ float cellP(float pi, float pf, float pg, float po, float& cs)
{
    float a = __builtin_amdgcn_exp2f(-pi);
    float u = __builtin_amdgcn_exp2f(-pf);
    float b = __builtin_amdgcn_exp2f(pg);
    float d = __builtin_amdgcn_exp2f(-po);
    float t1 = 1.0f + a;
    float t3 = 1.0f + u;
    float t2 = __builtin_fmaf(t1, b, t1);          // (1+a)(1+b)
    float bm = b - 1.0f;
    float num = __builtin_fmaf(L2E2 * bm, t3, cs * t2);
    cs = num * __builtin_amdgcn_rcpf(t2 * t3);
    float e = __builtin_amdgcn_exp2f(cs);
    float t4 = 1.0f + d;
    float t5 = __builtin_fmaf(t4, e, t4);          // (1+d)(1+e)
    return (e - 1.0f) * __builtin_amdgcn_rcpf(t5);
}

// gather this lane's gate value from the MFMA-layout bundle via 4 bpermutes + 3 selects
__device__ __forceinline__ float bperm_gate(int va, int selr, floatx4 Cg)
{
    int t0 = __builtin_amdgcn_ds_bpermute(va, __float_as_int(Cg[0]));
    int t1 = __builtin_amdgcn_ds_bpermute(va, __float_as_int(Cg[1]));
    int t2 = __builtin_amdgcn_ds_bpermute(va, __float_as_int(Cg[2]));
    int t3 = __builtin_amdgcn_ds_bpermute(va, __float_as_int(Cg[3]));
    int v01 = (selr & 1) ? t1 : t0;
    int v23 = (selr & 1) ? t3 : t2;
    int v = (selr & 2) ? v23 : v01;
    return __int_as_float(v);
}

__global__ __launch_bounds__(NT, 1) void lstm_fused(
    const float* __restrict__ x,
    const float* __restrict__ Wih0, const float* __restrict__ Whh0,
    const float* __restrict__ bih0, const float* __restrict__ bhh0,
    const float* __restrict__ Wih1, const float* __restrict__ Whh1,
    const float* __restrict__ bih1, const float* __restrict__ bhh1,
    float* __restrict__ h2last)
{
    // LDS: 64 + 8 + 8 + 2 = 82 KB
    __shared__ __align__(16) f16 whh1lds[8][4][2][64][8];  // [wg][gate][kt-2][lane][e]
    __shared__ __align__(16) f16 h1f[2][4][64][8];         // [buf][kt][lane][e] B-frag
    __shared__ __align__(16) f16 h2f[2][4][64][8];
    __shared__ __align__(16) f16 xf[2][64][8];             // x_aug (K=16: 14 x, 0, 1.0)

    const int tid = threadIdx.x;
    const int lane = tid & 63;
    const int wv = tid >> 6;          // wave 0..7 == j-group for BOTH layers
    const int n = lane & 15;          // batch column (valid < NB) / A-row index
    const int q = lane >> 4;          // quad -> rows q*4+r
    const int b0 = blockIdx.x * NB;

    // ---- zero state buffers: h1f,h2f = 4096 dwords total; xf = 512 dwords ----
    {
        unsigned int* z1 = (unsigned int*)h1f;
        unsigned int* z2 = (unsigned int*)h2f;
#pragma unroll
        for (int i = 0; i < 4; ++i) {
            z1[tid + i * 512] = 0u;
            z2[tid + i * 512] = 0u;
        }
        ((unsigned int*)xf)[tid] = 0u;
    }
    __syncthreads();

    // ---- x_aug constants (k==15 -> 1.0 in BOTH buffers) + stage x(0) into xf[0] ----
    if (tid < NB) {
        xf[0][tid + 16][7] = (f16)1.0f;
        xf[1][tid + 16][7] = (f16)1.0f;
    }
    if (tid < 64) {
        int nn_ = tid & 15, kq = tid >> 4;
        if (nn_ < NB && kq < 2) {
            half8 v;
#pragma unroll
            for (int e = 0; e < 8; ++e) {
                int k = kq * 8 + e;
                v[e] = (k < D_) ? (f16)x[(size_t)(b0 + nn_) * T_ * D_ + k]
                                : (k == 15 ? (f16)1.0f : (f16)0.0f);
            }
            *(half8*)&xf[0][tid][0] = v;
        }
    }

    // incremental x-prefetch pointer (valid only for threads < NB*D_)
    const float* xpp = x + (size_t)(b0 + (tid & 3)) * T_ * D_ + D_ + (tid >> 2);

    // ---- per-wave weights: layer-0 j-group wv AND layer-1 j-group wv ----
    const int wg = wv;
    half8 aWhh0[4][4], aWih0[4];      // layer-0: all in regs
    half8 aWih1[4][4], aWhh1r[4][2];  // layer-1: Wih1 + Whh1 kt0-1 regs; kt2-3 LDS
#pragma unroll
    for (int g = 0; g < 4; ++g) {
        const float gs = (g == 2) ? L2E2 : L2E;   // g-gate rows pre-scaled 2x
        const int gr = g * 128 + wg * 16 + n;
#pragma unroll
        for (int kt = 0; kt < 4; ++kt)
            aWhh0[g][kt] = ldfrag_s(Whh0 + (size_t)gr * H_ + kt * 32 + q * 8, gs);
        half8 w0;
#pragma unroll
        for (int e = 0; e < 8; ++e) {
            int k = q * 8 + e;
            if (k < D_)       w0[e] = (f16)(Wih0[(size_t)gr * D_ + k] * gs);
            else if (k == 15) w0[e] = (f16)((bih0[gr] + bhh0[gr]) * gs);
            else              w0[e] = (f16)0.0f;
        }
        aWih0[g] = w0;
#pragma unroll
        for (int kt = 0; kt < 4; ++kt) {
            aWih1[g][kt] = ldfrag_s(Wih1 + (size_t)gr * H_ + kt * 32 + q * 8, gs);
            half8 wf = ldfrag_s(Whh1 + (size_t)gr * H_ + kt * 32 + q * 8, gs);
            if (kt < 2) aWhh1r[g][kt] = wf;
            else        *(half8*)&whh1lds[wg][g][kt - 2][lane][0] = wf;
        }
    }

    // ---- per-lane (dest-cell) constants for the redistributed epilogue ----
    const int jj = lane & 15;         // dest cell row j within the wave's 16-row group
    const int nn = lane >> 4;         // dest cell batch column (0..3, all valid)
    const int va = (((jj >> 2) << 4) | nn) * 4;  // bpermute byte addr of source lane
    const int selr = jj & 3;                     // element index within source bundle
    const int qD = jj >> 2, rD = jj & 3;
    const int ktD = wg >> 1;
    const int rowD = nn + 16 * ((wg & 1) * 2 + (qD >> 1));
    const int eD = (qD & 1) * 4 + rD;
    float bias1v[4];
#pragma unroll
    for (int g = 0; g < 4; ++g) {
        const float gs = (g == 2) ? L2E2 : L2E;
        const int gb = g * 128 + wg * 16 + jj;
        bias1v[g] = (bih1[gb] + bhh1[gb]) * gs;
    }

    float cs1 = 0.0f;   // layer-0 cell state for cell (jj, nn), pre-scaled by 2*log2e
    float cs2 = 0.0f;   // layer-1 cell state
    __syncthreads();

    // phase p: layer-0 computes h1(p) [p<T], layer-1 computes h2(p-1) [p>=1]
    for (int p = 0; p <= T_; ++p) {
        const int cur = p & 1, nxt = cur ^ 1;
        const bool doA = (p < T_);
        const bool doB = (p >= 1);

        float xp = 0.0f;
        if (tid < NB * D_ && (p + 1) < T_) xp = *xpp;

        floatx4 C0[4], C1[4];
#pragma unroll
        for (int g = 0; g < 4; ++g) {
            C0[g] = floatx4{0.f, 0.f, 0.f, 0.f};
            C1[g] = floatx4{0.f, 0.f, 0.f, 0.f};
        }

        if (doA) {
            half8 bx = *(const half8*)&xf[cur][lane][0];
#pragma unroll
            for (int g = 0; g < 4; ++g) C0[g] = MFMA(aWih0[g], bx, C0[g]);
        }
        // shared h1f fragments: feed layer-0 recurrence AND layer-1 input
#pragma unroll
        for (int kt = 0; kt < 4; ++kt) {
            half8 bh = *(const half8*)&h1f[cur][kt][lane][0];
            if (doA) {
#pragma unroll
                for (int g = 0; g < 4; ++g) C0[g] = MFMA(aWhh0[g][kt], bh, C0[g]);
            }
            if (doB) {
#pragma unroll
                for (int g = 0; g < 4; ++g) C1[g] = MFMA(aWih1[g][kt], bh, C1[g]);
            }
        }
        if (doB) {
#pragma unroll
            for (int kt = 0; kt < 2; ++kt) {
                half8 bh = *(const half8*)&h2f[cur][kt][lane][0];
#pragma unroll
                for (int g = 0; g < 4; ++g) C1[g] = MFMA(aWhh1r[g][kt], bh, C1[g]);
            }
#pragma unroll
            for (int kt = 2; kt < 4; ++kt) {
                half8 bh = *(const half8*)&h2f[cur][kt][lane][0];
#pragma unroll
                for (int g = 0; g < 4; ++g) {
                    half8 aw = *(const half8*)&whh1lds[wg][g][kt - 2][lane][0];
                    C1[g] = MFMA(aw, bh, C1[g]);
                }
            }
        }

        // ---- layer-0 epilogue: bpermute gate bundles, one cellP per lane ----
        if (doA) {
            float g0 = bperm_gate(va, selr, C0[0]);
            float g1 = bperm_gate(va, selr, C0[1]);
            float g2 = bperm_gate(va, selr, C0[2]);
            float g3 = bperm_gate(va, selr, C0[3]);
            float h0 = cellP(g0, g1, g2, g3, cs1);
            h1f[nxt][ktD][rowD][eD] = (f16)h0;
        }

        // ---- layer-1 epilogue ----
        if (doB) {
            float g0 = bperm_gate(va, selr, C1[0]) + bias1v[0];
            float g1 = bperm_gate(va, selr, C1[1]) + bias1v[1];
            float g2 = bperm_gate(va, selr, C1[2]) + bias1v[2];
            float g3 = bperm_gate(va, selr, C1[3]) + bias1v[3];
            float hv = cellP(g0, g1, g2, g3, cs2);
            h2f[nxt][ktD][rowD][eD] = (f16)hv;
            if (p == T_)
                h2last[(size_t)(b0 + nn) * H_ + wg * 16 + jj] = hv;
        }

        if (tid < NB * D_ && (p + 1) < T_) {
            int k = tid >> 2;
            xf[nxt][(tid & 3) + 16 * (k >> 3)][k & 7] = (f16)xp;
            xpp += D_;
        }
        __syncthreads();
    }
}

// batch-norm statistics over the batch dim: 1 block, 1024 threads
__global__ void bn_stats(const float* __restrict__ h2last, float* __restrict__ stats)
{
    __shared__ float red[2][8][128];
    const int tid = threadIdx.x;
    const int j = tid & 127, bs = tid >> 7;
    float s = 0.0f, ss = 0.0f;
    for (int bb = 0; bb < 128; ++bb) {
        float v = h2last[(size_t)(bb * 8 + bs) * H_ + j];
        s += v;
        ss += v * v;
    }
    red[0][bs][j] = s;
    red[1][bs][j] = ss;
    __syncthreads();
    if (tid < 128) {
        float S = 0.0f, SS = 0.0f;
#pragma unroll
        for (int k = 0; k < 8; ++k) { S += red[0][k][tid]; SS += red[1][k][tid]; }
        float mu = S * (1.0f / 1024.0f);
        float var = SS * (1.0f / 1024.0f) - mu * mu;
        stats[tid] = mu;
        stats[128 + tid] = __builtin_amdgcn_rsqf(var + 1e-5f);
    }
}

// normalize + MLP head: 8 blocks x 128 threads, one batch element per thread
__global__ void bn_mlp(const float* __restrict__ h2last, const float* __restrict__ stats,
                       const float* __restrict__ gamma, const float* __restrict__ beta,
                       const float* __restrict__ W1, const float* __restrict__ b1,
                       const float* __restrict__ W2, const float* __restrict__ b2,
                       float* __restrict__ out)
{
    __shared__ float W1T[128][33];
    __shared__ float mus[128], isds[128], gs[128], bts[128], w2s[32];
    const int tid = threadIdx.x;
    const int b = blockIdx.x * 128 + tid;

    for (int i = tid; i < 4096; i += 128) {
        int k = i >> 7, j = i & 127;
        W1T[j][k] = W1[i];
    }
    mus[tid] = stats[tid];
    isds[tid] = stats[128 + tid];
    gs[tid] = gamma[tid];
    bts[tid] = beta[tid];
    if (tid < 32) w2s[tid] = W2[tid];
    __syncthreads();

    float z[32];
#pragma unroll
    for (int k = 0; k < 32; ++k) z[k] = b1[k];

    for (int j = 0; j < 128; ++j) {
        float nv = (h2last[(size_t)b * H_ + j] - mus[j]) * isds[j] * gs[j] + bts[j];
#pragma unroll
        for (int k = 0; k < 32; ++k) z[k] += W1T[j][k] * nv;
    }
    float o = b2[0];
#pragma unroll
    for (int k = 0; k < 32; ++k) o += w2s[k] * fmaxf(z[k], 0.0f);
    out[b] = o;
}

extern "C" void kernel_launch(void* const* d_in, const int* in_sizes, int n_in,
                              void* d_out, int out_size, void* d_ws, size_t ws_size,
                              hipStream_t stream)
{
    const float* x    = (const float*)d_in[0];
    const float* Wih0 = (const float*)d_in[1];
    const float* Whh0 = (const float*)d_in[2];
    const float* bih0 = (const float*)d_in[3];
    const float* bhh0 = (const float*)d_in[4];
    const float* Wih1 = (const float*)d_in[5];
    const float* Whh1 = (const float*)d_in[6];
    const float* bih1 = (const float*)d_in[7];
    const float* bhh1 = (const float*)d_in[8];
    const float* gamma = (const float*)d_in[9];
    const float* beta  = (const float*)d_in[10];
    const float* W1 = (const float*)d_in[11];
    const float* b1 = (const float*)d_in[12];
    const float* W2 = (const float*)d_in[13];
    const float* b2 = (const float*)d_in[14];

    float* h2last = (float*)d_ws;              // 1024*128 floats = 512 KB
    float* stats  = h2last + (size_t)B_ * H_;  // 256 floats
    float* out = (float*)d_out;

    hipLaunchKernelGGL(lstm_fused, dim3(B_ / NB), dim3(NT), 0, stream,
                       x, Wih0, Whh0, bih0, bhh0, Wih1, Whh1, bih1, bhh1, h2last);
    hipLaunchKernelGGL(bn_stats, dim3(1), dim3(1024), 0, stream, h2last, stats);
    hipLaunchKernelGGL(bn_mlp, dim3(8), dim3(128), 0, stream,
                       h2last, stats, gamma, beta, W1, b1, W2, b2, out);
}

// Round 8
// 959.698 us; speedup vs baseline: 1.0327x; 1.0327x over previous
//
#include <hip/hip_runtime.h>

// ForexLSTM: 2-layer LSTM (B=1024, T=512, D=14, H=128) + batchnorm-over-batch + MLP(128->32->1)
//
// Round 18: R16 verbatim + amdgpu_num_vgpr(256). Allocation model (from R14/R16/R17
// counter fingerprint): the backend live-range-SPLITS the ~176 loop-invariant weight
// VGPRs (scratch stores once at init = WRITE 66.5MB = ~508B/thread; per-phase re-fills
// hit L1/L2, +22MB HBM fetch = miss fraction) to chase a 4-waves/EU / 128-VGPR target.
// The redistribution epilogue (early accumulator death, short VALU tail) lowers the
// pressure estimate enough to trigger this; R12's fat epilogue masked it (got 256).
// R17 proved the trigger is NOT the in-loop asm (bpermute build, no asm, still 128,
// and bpermute's LDS-crossbar traffic made it worse: 991us, conflicts 71M).
//   - amdgpu_num_vgpr(256): pin the RA budget directly; no occupancy target to serve
//     -> no reason to split the weight live ranges.
//   - Rest identical to R16 (948us, best measured): cellP redistribution via padded
//     cred LDS (stride 40: reads (8nn+jj)%32 exact 2-way free, b128 writes 2-way free),
//     one cellP per lane (VALUBusy 38->23 proven), setprio around MFMA cluster,
//     Whh1 kt0-1 regs / kt2-3 LDS, fused-reciprocal cellP (5 exp2 + 2 rcp),
//     wave-role merge, incremental x prefetch.

#define B_ 1024
#define T_ 512
#define D_ 14
#define H_ 128
#define NB 4
#define NT 512

#define L2E 1.44269504088896f
#define L2E2 2.88539008177793f

typedef _Float16 f16;
typedef _Float16 half4 __attribute__((ext_vector_type(4)));
typedef _Float16 half8 __attribute__((ext_vector_type(8)));
typedef float floatx4 __attribute__((ext_vector_type(4)));

__device__ __forceinline__ half8 ldfrag_s(const float* __restrict__ p, float s) {
    half8 r;
#pragma unroll
    for (int j = 0; j < 8; ++j) r[j] = (f16)(p[j] * s);
    return r;
}

#define MFMA(a, b, c) __builtin_amdgcn_mfma_f32_16x16x32_f16((a), (b), (c), 0, 0, 0)

// Fused LSTM cell epilogue on pre-scaled gates:
//   pi,pf,po = y*log2e ; pg = 2x*log2e ; cs = 2*log2e*c (scaled cell state, updated).
// Returns h in true units. 5 exp2 + 2 rcp.
__device__ __forceinline__ float cellP(float pi, float pf, float pg, float po, float& cs)
{
    float a = __builtin_amdgcn_exp2f(-pi);
    float u = __builtin_amdgcn_exp2f(-pf);
    float b = __builtin_amdgcn_exp2f(pg);
    float d = __builtin_amdgcn_exp2f(-po);
    float t1 = 1.0f + a;
    float t3 = 1.0f + u;
    float t2 = __builtin_fmaf(t1, b, t1);          // (1+a)(1+b)
    float bm = b - 1.0f;
    float num = __builtin_fmaf(L2E2 * bm, t3, cs * t2);
    cs = num * __builtin_amdgcn_rcpf(t2 * t3);
    float e = __builtin_amdgcn_exp2f(cs);
    float t4 = 1.0f + d;
    float t5 = __builtin_fmaf(t4, e, t4);          // (1+d)(1+e)
    return (e - 1.0f) * __builtin_amdgcn_rcpf(t5);
}

__attribute__((amdgpu_num_vgpr(256)))
__global__ __launch_bounds__(NT)
void lstm_fused(
    const float* __restrict__ x,
    const float* __restrict__ Wih0, const float* __restrict__ Whh0,
    const float* __restrict__ bih0, const float* __restrict__ bhh0,
    const float* __restrict__ Wih1, const float* __restrict__ Whh1,
    const float* __restrict__ bih1, const float* __restrict__ bhh1,
    float* __restrict__ h2last)
{
    // LDS: 64 + 8 + 8 + 2 + 20 + 20 = 122 KB
    __shared__ __align__(16) f16 whh1lds[8][4][2][64][8];  // [wg][gate][kt-2][lane][e]
    __shared__ __align__(16) f16 h1f[2][4][64][8];         // [buf][kt][lane][e] B-frag
    __shared__ __align__(16) f16 h2f[2][4][64][8];
    __shared__ __align__(16) f16 xf[2][64][8];             // x_aug (K=16: 14 x, 0, 1.0)
    __shared__ __align__(16) float credA[8][4][4][40];     // [wv][gate][n][j(pad 40)] L0
    __shared__ __align__(16) float credB[8][4][4][40];     // [wv][gate][n][j(pad 40)] L1

    const int tid = threadIdx.x;
    const int lane = tid & 63;
    const int wv = tid >> 6;          // wave 0..7 == j-group for BOTH layers
    const int n = lane & 15;          // batch column (valid < NB) / A-row index
    const int q = lane >> 4;          // quad -> rows q*4+r
    const int b0 = blockIdx.x * NB;

    // ---- zero state buffers: h1f,h2f = 4096 dwords total; xf = 512 dwords ----
    {
        unsigned int* z1 = (unsigned int*)h1f;
        unsigned int* z2 = (unsigned int*)h2f;
#pragma unroll
        for (int i = 0; i < 4; ++i) {
            z1[tid + i * 512] = 0u;
            z2[tid + i * 512] = 0u;
        }
        ((unsigned int*)xf)[tid] = 0u;
    }
    __syncthreads();

    // ---- x_aug constants (k==15 -> 1.0 in BOTH buffers) + stage x(0) into xf[0] ----
    if (tid < NB) {
        xf[0][tid + 16][7] = (f16)1.0f;
        xf[1][tid + 16][7] = (f16)1.0f;
    }
    if (tid < 64) {
        int nn_ = tid & 15, kq = tid >> 4;
        if (nn_ < NB && kq < 2) {
            half8 v;
#pragma unroll
            for (int e = 0; e < 8; ++e) {
                int k = kq * 8 + e;
                v[e] = (k < D_) ? (f16)x[(size_t)(b0 + nn_) * T_ * D_ + k]
                                : (k == 15 ? (f16)1.0f : (f16)0.0f);
            }
            *(half8*)&xf[0][tid][0] = v;
        }
    }

    // incremental x-prefetch pointer (valid only for threads < NB*D_)
    const float* xpp = x + (size_t)(b0 + (tid & 3)) * T_ * D_ + D_ + (tid >> 2);

    // ---- per-wave weights: layer-0 j-group wv AND layer-1 j-group wv ----
    const int wg = wv;
    half8 aWhh0[4][4], aWih0[4];      // layer-0: all in regs
    half8 aWih1[4][4], aWhh1r[4][2];  // layer-1: Wih1 + Whh1 kt0-1 regs; kt2-3 LDS
#pragma unroll
    for (int g = 0; g < 4; ++g) {
        const float gs = (g == 2) ? L2E2 : L2E;   // g-gate rows pre-scaled 2x
        const int gr = g * 128 + wg * 16 + n;
#pragma unroll
        for (int kt = 0; kt < 4; ++kt)
            aWhh0[g][kt] = ldfrag_s(Whh0 + (size_t)gr * H_ + kt * 32 + q * 8, gs);
        half8 w0;
#pragma unroll
        for (int e = 0; e < 8; ++e) {
            int k = q * 8 + e;
            if (k < D_)       w0[e] = (f16)(Wih0[(size_t)gr * D_ + k] * gs);
            else if (k == 15) w0[e] = (f16)((bih0[gr] + bhh0[gr]) * gs);
            else              w0[e] = (f16)0.0f;
        }
        aWih0[g] = w0;
#pragma unroll
        for (int kt = 0; kt < 4; ++kt) {
            aWih1[g][kt] = ldfrag_s(Wih1 + (size_t)gr * H_ + kt * 32 + q * 8, gs);
            half8 wf = ldfrag_s(Whh1 + (size_t)gr * H_ + kt * 32 + q * 8, gs);
            if (kt < 2) aWhh1r[g][kt] = wf;
            else        *(half8*)&whh1lds[wg][g][kt - 2][lane][0] = wf;
        }
    }

    // ---- per-lane (dest-cell) constants for the redistributed epilogue ----
    const int jj = lane & 15;         // dest cell row j within the wave's 16-row group
    const int nn = lane >> 4;         // dest cell batch column (0..3, all valid)
    const int qD = jj >> 2, rD = jj & 3;
    const int ktD = wg >> 1;
    const int rowD = nn + 16 * ((wg & 1) * 2 + (qD >> 1));
    const int eD = (qD & 1) * 4 + rD;
    float bias1v[4];
#pragma unroll
    for (int g = 0; g < 4; ++g) {
        const float gs = (g == 2) ? L2E2 : L2E;
        const int gb = g * 128 + wg * 16 + jj;
        bias1v[g] = (bih1[gb] + bhh1[gb]) * gs;
    }

    float cs1 = 0.0f;   // layer-0 cell state for cell (jj, nn), pre-scaled by 2*log2e
    float cs2 = 0.0f;   // layer-1 cell state
    __syncthreads();

    // phase p: layer-0 computes h1(p) [p<T], layer-1 computes h2(p-1) [p>=1]
    for (int p = 0; p <= T_; ++p) {
        const int cur = p & 1, nxt = cur ^ 1;
        const bool doA = (p < T_);
        const bool doB = (p >= 1);

        float xp = 0.0f;
        if (tid < NB * D_ && (p + 1) < T_) xp = *xpp;

        floatx4 C0[4], C1[4];
#pragma unroll
        for (int g = 0; g < 4; ++g) {
            C0[g] = floatx4{0.f, 0.f, 0.f, 0.f};
            C1[g] = floatx4{0.f, 0.f, 0.f, 0.f};
        }

        __builtin_amdgcn_s_setprio(1);
        if (doA) {
            half8 bx = *(const half8*)&xf[cur][lane][0];
#pragma unroll
            for (int g = 0; g < 4; ++g) C0[g] = MFMA(aWih0[g], bx, C0[g]);
        }
        // shared h1f fragments: feed layer-0 recurrence AND layer-1 input
#pragma unroll
        for (int kt = 0; kt < 4; ++kt) {
            half8 bh = *(const half8*)&h1f[cur][kt][lane][0];
            if (doA) {
#pragma unroll
                for (int g = 0; g < 4; ++g) C0[g] = MFMA(aWhh0[g][kt], bh, C0[g]);
            }
            if (doB) {
#pragma unroll
                for (int g = 0; g < 4; ++g) C1[g] = MFMA(aWih1[g][kt], bh, C1[g]);
            }
        }
        if (doB) {
#pragma unroll
            for (int kt = 0; kt < 2; ++kt) {
                half8 bh = *(const half8*)&h2f[cur][kt][lane][0];
#pragma unroll
                for (int g = 0; g < 4; ++g) C1[g] = MFMA(aWhh1r[g][kt], bh, C1[g]);
            }
#pragma unroll
            for (int kt = 2; kt < 4; ++kt) {
                half8 bh = *(const half8*)&h2f[cur][kt][lane][0];
#pragma unroll
                for (int g = 0; g < 4; ++g) {
                    half8 aw = *(const half8*)&whh1lds[wg][g][kt - 2][lane][0];
                    C1[g] = MFMA(aw, bh, C1[g]);
                }
            }
        }
        __builtin_amdgcn_s_setprio(0);

        // ---- layer-0 epilogue: redistribute 4-gate bundles, one cellP per lane ----
        if (doA) {
            if (n < NB) {
#pragma unroll
                for (int g = 0; g < 4; ++g)
                    *(floatx4*)&credA[wv][g][n][q * 4] = C0[g];
            }
            asm volatile("s_waitcnt lgkmcnt(0)" ::: "memory");
            __builtin_amdgcn_sched_barrier(0);
            float g0 = credA[wv][0][nn][jj];
            float g1 = credA[wv][1][nn][jj];
            float g2 = credA[wv][2][nn][jj];
            float g3 = credA[wv][3][nn][jj];
            float h0 = cellP(g0, g1, g2, g3, cs1);
            h1f[nxt][ktD][rowD][eD] = (f16)h0;
        }

        // ---- layer-1 epilogue ----
        if (doB) {
            if (n < NB) {
#pragma unroll
                for (int g = 0; g < 4; ++g)
                    *(floatx4*)&credB[wv][g][n][q * 4] = C1[g];
            }
            asm volatile("s_waitcnt lgkmcnt(0)" ::: "memory");
            __builtin_amdgcn_sched_barrier(0);
            float g0 = credB[wv][0][nn][jj] + bias1v[0];
            float g1 = credB[wv][1][nn][jj] + bias1v[1];
            float g2 = credB[wv][2][nn][jj] + bias1v[2];
            float g3 = credB[wv][3][nn][jj] + bias1v[3];
            float hv = cellP(g0, g1, g2, g3, cs2);
            h2f[nxt][ktD][rowD][eD] = (f16)hv;
            if (p == T_)
                h2last[(size_t)(b0 + nn) * H_ + wg * 16 + jj] = hv;
        }

        if (tid < NB * D_ && (p + 1) < T_) {
            int k = tid >> 2;
            xf[nxt][(tid & 3) + 16 * (k >> 3)][k & 7] = (f16)xp;
            xpp += D_;
        }
        __syncthreads();
    }
}

// batch-norm statistics over the batch dim: 1 block, 1024 threads
__global__ void bn_stats(const float* __restrict__ h2last, float* __restrict__ stats)
{
    __shared__ float red[2][8][128];
    const int tid = threadIdx.x;
    const int j = tid & 127, bs = tid >> 7;
    float s = 0.0f, ss = 0.0f;
    for (int bb = 0; bb < 128; ++bb) {
        float v = h2last[(size_t)(bb * 8 + bs) * H_ + j];
        s += v;
        ss += v * v;
    }
    red[0][bs][j] = s;
    red[1][bs][j] = ss;
    __syncthreads();
    if (tid < 128) {
        float S = 0.0f, SS = 0.0f;
#pragma unroll
        for (int k = 0; k < 8; ++k) { S += red[0][k][tid]; SS += red[1][k][tid]; }
        float mu = S * (1.0f / 1024.0f);
        float var = SS * (1.0f / 1024.0f) - mu * mu;
        stats[tid] = mu;
        stats[128 + tid] = __builtin_amdgcn_rsqf(var + 1e-5f);
    }
}

// normalize + MLP head: 8 blocks x 128 threads, one batch element per thread
__global__ void bn_mlp(const float* __restrict__ h2last, const float* __restrict__ stats,
                       const float* __restrict__ gamma, const float* __restrict__ beta,
                       const float* __restrict__ W1, const float* __restrict__ b1,
                       const float* __restrict__ W2, const float* __restrict__ b2,
                       float* __restrict__ out)
{
    __shared__ float W1T[128][33];
    __shared__ float mus[128], isds[128], gs[128], bts[128], w2s[32];
    const int tid = threadIdx.x;
    const int b = blockIdx.x * 128 + tid;

    for (int i = tid; i < 4096; i += 128) {
        int k = i >> 7, j = i & 127;
        W1T[j][k] = W1[i];
    }
    mus[tid] = stats[tid];
    isds[tid] = stats[128 + tid];
    gs[tid] = gamma[tid];
    bts[tid] = beta[tid];
    if (tid < 32) w2s[tid] = W2[tid];
    __syncthreads();

    float z[32];
#pragma unroll
    for (int k = 0; k < 32; ++k) z[k] = b1[k];

    for (int j = 0; j < 128; ++j) {
        float nv = (h2last[(size_t)b * H_ + j] - mus[j]) * isds[j] * gs[j] + bts[j];
#pragma unroll
        for (int k = 0; k < 32; ++k) z[k] += W1T[j][k] * nv;
    }
    float o = b2[0];
#pragma unroll
    for (int k = 0; k < 32; ++k) o += w2s[k] * fmaxf(z[k], 0.0f);
    out[b] = o;
}

extern "C" void kernel_launch(void* const* d_in, const int* in_sizes, int n_in,
                              void* d_out, int out_size, void* d_ws, size_t ws_size,
                              hipStream_t stream)
{
    const float* x    = (const float*)d_in[0];
    const float* Wih0 = (const float*)d_in[1];
    const float* Whh0 = (const float*)d_in[2];
    const float* bih0 = (const float*)d_in[3];
    const float* bhh0 = (const float*)d_in[4];
    const float* Wih1 = (const float*)d_in[5];
    const float* Whh1 = (const float*)d_in[6];
    const float* bih1 = (const float*)d_in[7];
    const float* bhh1 = (const float*)d_in[8];
    const float* gamma = (const float*)d_in[9];
    const float* beta  = (const float*)d_in[10];
    const float* W1 = (const float*)d_in[11];
    const float* b1 = (const float*)d_in[12];
    const float* W2 = (const float*)d_in[13];
    const float* b2 = (const float*)d_in[14];

    float* h2last = (float*)d_ws;              // 1024*128 floats = 512 KB
    float* stats  = h2last + (size_t)B_ * H_;  // 256 floats
    float* out = (float*)d_out;

    hipLaunchKernelGGL(lstm_fused, dim3(B_ / NB), dim3(NT), 0, stream,
                       x, Wih0, Whh0, bih0, bhh0, Wih1, Whh1, bih1, bhh1, h2last);
    hipLaunchKernelGGL(bn_stats, dim3(1), dim3(1024), 0, stream, h2last, stats);
    hipLaunchKernelGGL(bn_mlp, dim3(8), dim3(128), 0, stream,
                       h2last, stats, gamma, beta, W1, b1, W2, b2, out);
}